// Round 2
// baseline (6034.063 us; speedup 1.0000x reference)
//
#include <hip/hip_runtime.h>
#include <cstdint>
#include <cstddef>

#define B_ 256
#define L_ 200
#define S_ 199
#define D_ 256
#define Q_ 20000
#define C_ 500

// ---- workspace layout (bytes, all 256-aligned) ----
#define OFF_TEPF 0u            // 200*256*4 = 204800
#define OFF_TESF 204800u       // 204800
#define OFF_CAF  409600u       // 1024
#define OFF_PPF  410624u       // 64*256*8  = 131072  (Wpf left half, bf16x4 packed)
#define OFF_PSF  541696u       // 131072
#define OFF_PAF  672768u       // 131072
#define OFF_PAS  803840u       // 128*256*8 = 262144
#define OFF_PPS  1065984u      // 262144
#define OFF_PSS  1328128u      // 262144
#define OFF_PO1  1590272u      // 256*256*8 = 524288
#define OFF_PS   2114560u      // 256*199*256*4 = 52166656
#define OFF_SS   54281216u     // 52166656
// total = 106,447,872 bytes (~101.5 MB)

__device__ __forceinline__ unsigned bf16_rne(float f) {
  unsigned u = __float_as_uint(f);
  return (u + 0x7fffu + ((u >> 16) & 1u)) >> 16;
}

// TEpf[tau][d] = bpf[d] + sum_k time_embed[tau][k] * Wpf[d][256+k]; same for sf.
__global__ void te_kernel(const float* __restrict__ te,
                          const float* __restrict__ Wpf, const float* __restrict__ bpf,
                          const float* __restrict__ Wsf, const float* __restrict__ bsf,
                          float* __restrict__ TEpf, float* __restrict__ TEsf) {
  int idx = blockIdx.x * 256 + threadIdx.x;   // grid = 200 blocks -> exact
  int tau = idx >> 8, d = idx & 255;
  const float* ter = te + (tau << 8);
  const float* wp = Wpf + d * 512 + 256;
  const float* ws = Wsf + d * 512 + 256;
  float ap = 0.f, as = 0.f;
  for (int k = 0; k < 256; ++k) {
    float x = ter[k];
    ap = fmaf(x, wp[k], ap);
    as = fmaf(x, ws[k], as);
  }
  TEpf[idx] = ap + bpf[d];
  TEsf[idx] = as + bsf[d];
}

// CAF[d] = baf[d] + sum_k time_embed[1][k] * Waf[d][256+k]
__global__ void caf_kernel(const float* __restrict__ te, const float* __restrict__ Waf,
                           const float* __restrict__ baf, float* __restrict__ CAF) {
  int d = threadIdx.x;
  const float* ter = te + 256;
  const float* wa = Waf + d * 512 + 256;
  float a = 0.f;
  for (int k = 0; k < 256; ++k) a = fmaf(ter[k], wa[k], a);
  CAF[d] = a + baf[d];
}

// Pack W[d][4k4..4k4+3] (fp32, row-major (256,fi)) -> out[k4*256+d] as 4x bf16 in uint2.
__global__ void pack_kernel(const float* __restrict__ W, uint2* __restrict__ out, int fi) {
  int k4 = blockIdx.x, d = threadIdx.x;
  const float* r = W + d * fi + (k4 << 2);
  unsigned p0 = bf16_rne(r[0]) | (bf16_rne(r[1]) << 16);
  unsigned p1 = bf16_rne(r[2]) | (bf16_rne(r[3]) << 16);
  out[k4 * 256 + d] = make_uint2(p0, p1);
}

__device__ __forceinline__ float upfma(uint2 w, float4 x, float acc) {
  acc = fmaf(__uint_as_float(w.x << 16), x.x, acc);
  acc = fmaf(__uint_as_float(w.x & 0xffff0000u), x.y, acc);
  acc = fmaf(__uint_as_float(w.y << 16), x.z, acc);
  acc = fmaf(__uint_as_float(w.y & 0xffff0000u), x.w, acc);
  return acc;
}

__device__ __forceinline__ float sigf(float z) { return 1.f / (1.f + __expf(-z)); }
__device__ __forceinline__ float tanh_fast(float z) { return 1.f - 2.f / (__expf(2.f * z) + 1.f); }

__global__ __launch_bounds__(256)
void scan_kernel(const int* __restrict__ q_seq, const int* __restrict__ c_seq,
                 const int* __restrict__ a_seq,
                 const float* __restrict__ pro_embed, const float* __restrict__ skill_embed,
                 const float* __restrict__ ans_embed,
                 const float* __restrict__ ls_state,
                 const float* __restrict__ pro_state0, const float* __restrict__ skill_state0,
                 const float* __restrict__ akt_diff, const float* __restrict__ akt_change,
                 const float* __restrict__ TEpf, const float* __restrict__ TEsf,
                 const float* __restrict__ CAF,
                 const uint2* __restrict__ Ppf, const uint2* __restrict__ Psf,
                 const uint2* __restrict__ Paf,
                 const uint2* __restrict__ Pas, const uint2* __restrict__ Pps,
                 const uint2* __restrict__ Pss, const uint2* __restrict__ Po1,
                 const float* __restrict__ bas, const float* __restrict__ bps,
                 const float* __restrict__ bss, const float* __restrict__ bo1,
                 const float* __restrict__ Wo2, const float* __restrict__ bo2,
                 float* __restrict__ ps, float* __restrict__ ss,
                 float* __restrict__ out) {
  const int b = blockIdx.x;
  const int d = threadIdx.x;

  __shared__ float s_ast[256], s_lp[256], s_lc[256], s_tge[256], s_ctge[256];
  __shared__ float s_pe[256], s_x[256], s_la[256], s_lp2[256], s_lc2[256];
  __shared__ float s_caf[256], s_wo2[256], s_bas[256], s_bps[256], s_bss[256], s_bo1[256];
  __shared__ int s_lqt[Q_];   // last-seen step per question (80 KB, fits 160 KB LDS)
  __shared__ int s_lct[C_];
  __shared__ float s_red[4];

  // ---- init ----
  s_ast[d] = ls_state[d];
  s_caf[d] = CAF[d];
  s_wo2[d] = Wo2[d];
  s_bas[d] = bas[d]; s_bps[d] = bps[d]; s_bss[d] = bss[d]; s_bo1[d] = bo1[d];
  s_lct[d] = 0;
  if (d + 256 < C_) s_lct[d + 256] = 0;
#pragma clang loop unroll(disable)
  for (int i = d; i < Q_; i += 256) s_lqt[i] = 0;

  float* psb = ps + (size_t)b * S_ * D_;
  float* ssb = ss + (size_t)b * S_ * D_;
  psb[d] = pro_state0[d];     // only row 0 of the init state is ever read
  ssb[d] = skill_state0[d];
  const int* qs = q_seq + b * L_;
  const int* cs = c_seq + b * L_;
  const int* as_ = a_seq + b * L_;
  const float bo2v = bo2[0];
  __syncthreads();

#pragma clang loop unroll(disable)
  for (int t = 0; t < S_; ++t) {
    const int ip = qs[t + 1];
    const int ic = cs[t + 1];
    const int ia = as_[t + 1];
    const int lp_t = s_lqt[ip];
    const int lc_t = s_lct[ic];

    // ---- stage step inputs into LDS ----
    s_lp[d]  = psb[lp_t * D_ + d];
    s_lc[d]  = ssb[lc_t * D_ + d];
    s_tge[d] = TEpf[(t - lp_t) * D_ + d];   // includes right-half matmul + bias
    s_ctge[d]= TEsf[(t - lc_t) * D_ + d];
    float pe = pro_embed[ip * D_ + d] + skill_embed[ic * D_ + d]
             + akt_diff[ip] * akt_change[ic * D_ + d];
    s_pe[d] = pe;
    s_x[d]  = pe + ans_embed[ia * D_ + d];
    __syncthreads();   // sync A

    // ---- gate phase: 3 concurrent K=256 dots ----
    float a0 = 0.f, a1 = 0.f, a2 = 0.f;
    {
      const float4* xp = (const float4*)s_lp;
      const float4* xs = (const float4*)s_lc;
      const float4* xa = (const float4*)s_ast;
#pragma unroll 4
      for (int k = 0; k < 64; ++k) {
        a0 = upfma(Ppf[k * 256 + d], xp[k], a0);
        a1 = upfma(Psf[k * 256 + d], xs[k], a1);
        a2 = upfma(Paf[k * 256 + d], xa[k], a2);
      }
    }
    const float lp2 = s_lp[d]  * sigf(a0 + s_tge[d]);
    const float lc2 = s_lc[d]  * sigf(a1 + s_ctge[d]);
    const float la2 = s_ast[d] * sigf(a2 + s_caf[d]);
    s_la[d] = la2; s_lp2[d] = lp2; s_lc2[d] = lc2;
    if (d == 0) { s_lqt[ip] = t; s_lct[ic] = t; }  // all reads completed before sync A
    __syncthreads();   // sync B

    // ---- phase B: Wo1 (K=1024) + Was/Wps/Wss (K=512 each), interleaved ----
    float accO = 0.f, accA = 0.f, accP = 0.f, accC = 0.f;
    {
      const float4* xla = (const float4*)s_la;
      const float4* xlp = (const float4*)s_lp2;
      const float4* xlc = (const float4*)s_lc2;
      const float4* xpe = (const float4*)s_pe;
      const float4* xx  = (const float4*)s_x;
#pragma unroll 4
      for (int k = 0; k < 64; ++k) {
        float4 v = xla[k];
        accO = upfma(Po1[k * 256 + d], v, accO);
        accA = upfma(Pas[k * 256 + d], v, accA);
      }
#pragma unroll 4
      for (int k = 0; k < 64; ++k) {
        float4 v = xlp[k];
        accO = upfma(Po1[(64 + k) * 256 + d], v, accO);
        accP = upfma(Pps[k * 256 + d], v, accP);
      }
#pragma unroll 4
      for (int k = 0; k < 64; ++k) {
        float4 v = xlc[k];
        accO = upfma(Po1[(128 + k) * 256 + d], v, accO);
        accC = upfma(Pss[k * 256 + d], v, accC);
      }
#pragma unroll 4
      for (int k = 0; k < 64; ++k) {
        float4 v = xpe[k];
        accO = upfma(Po1[(192 + k) * 256 + d], v, accO);
      }
#pragma unroll 4
      for (int k = 0; k < 64; ++k) {
        float4 v = xx[k];
        accA = upfma(Pas[(64 + k) * 256 + d], v, accA);
        accP = upfma(Pps[(64 + k) * 256 + d], v, accP);
        accC = upfma(Pss[(64 + k) * 256 + d], v, accC);
      }
    }

    const float o1 = fmaxf(accO + s_bo1[d], 0.f);
    float r = o1 * s_wo2[d];
#pragma unroll
    for (int off = 32; off; off >>= 1) r += __shfl_down(r, off);

    const float a_new = la2 + tanh_fast(accA + s_bas[d]);
    const float p_new = lp2 + tanh_fast(accP + s_bps[d]);
    const float c_new = lc2 + tanh_fast(accC + s_bss[d]);
    psb[t * D_ + d] = p_new;
    ssb[t * D_ + d] = c_new;
    s_ast[d] = a_new;                       // next read is after sync C
    if ((d & 63) == 0) s_red[d >> 6] = r;
    __syncthreads();   // sync C
    if (d == 0) {
      float z = s_red[0] + s_red[1] + s_red[2] + s_red[3] + bo2v;
      out[b * S_ + t] = 1.f / (1.f + __expf(-z));
    }
  }
}

extern "C" void kernel_launch(void* const* d_in, const int* in_sizes, int n_in,
                              void* d_out, int out_size, void* d_ws, size_t ws_size,
                              hipStream_t stream) {
  const int*   q_seq        = (const int*)d_in[0];
  const int*   c_seq        = (const int*)d_in[1];
  const int*   a_seq        = (const int*)d_in[2];
  const float* pro_embed    = (const float*)d_in[3];
  const float* skill_embed  = (const float*)d_in[4];
  const float* ans_embed    = (const float*)d_in[5];
  const float* time_embed   = (const float*)d_in[6];
  const float* ls_state     = (const float*)d_in[7];
  const float* pro_state0   = (const float*)d_in[8];
  const float* skill_state0 = (const float*)d_in[9];
  const float* akt_diff     = (const float*)d_in[10];
  const float* akt_change   = (const float*)d_in[11];
  const float* Wpf = (const float*)d_in[12]; const float* bpf = (const float*)d_in[13];
  const float* Wps = (const float*)d_in[14]; const float* bps = (const float*)d_in[15];
  const float* Wsf = (const float*)d_in[16]; const float* bsf = (const float*)d_in[17];
  const float* Wss = (const float*)d_in[18]; const float* bss = (const float*)d_in[19];
  const float* Waf = (const float*)d_in[20]; const float* baf = (const float*)d_in[21];
  const float* Was = (const float*)d_in[22]; const float* bas = (const float*)d_in[23];
  const float* Wo1 = (const float*)d_in[24]; const float* bo1 = (const float*)d_in[25];
  const float* Wo2 = (const float*)d_in[26]; const float* bo2 = (const float*)d_in[27];

  char* ws = (char*)d_ws;
  float* TEpf = (float*)(ws + OFF_TEPF);
  float* TEsf = (float*)(ws + OFF_TESF);
  float* CAF  = (float*)(ws + OFF_CAF);
  uint2* Ppf  = (uint2*)(ws + OFF_PPF);
  uint2* Psf  = (uint2*)(ws + OFF_PSF);
  uint2* Paf  = (uint2*)(ws + OFF_PAF);
  uint2* Pas  = (uint2*)(ws + OFF_PAS);
  uint2* Pps  = (uint2*)(ws + OFF_PPS);
  uint2* Pss  = (uint2*)(ws + OFF_PSS);
  uint2* Po1  = (uint2*)(ws + OFF_PO1);
  float* ps   = (float*)(ws + OFF_PS);
  float* ssb  = (float*)(ws + OFF_SS);
  float* out  = (float*)d_out;

  te_kernel<<<200, 256, 0, stream>>>(time_embed, Wpf, bpf, Wsf, bsf, TEpf, TEsf);
  caf_kernel<<<1, 256, 0, stream>>>(time_embed, Waf, baf, CAF);

  // gate matrices: left half only (state part), K=256 -> 64 k4-blocks
  pack_kernel<<<64, 256, 0, stream>>>(Wpf, Ppf, 512);
  pack_kernel<<<64, 256, 0, stream>>>(Wsf, Psf, 512);
  pack_kernel<<<64, 256, 0, stream>>>(Waf, Paf, 512);
  // full K=512 update matrices
  pack_kernel<<<128, 256, 0, stream>>>(Was, Pas, 512);
  pack_kernel<<<128, 256, 0, stream>>>(Wps, Pps, 512);
  pack_kernel<<<128, 256, 0, stream>>>(Wss, Pss, 512);
  // Wo1: K=1024
  pack_kernel<<<256, 256, 0, stream>>>(Wo1, Po1, 1024);

  scan_kernel<<<B_, 256, 0, stream>>>(q_seq, c_seq, a_seq,
                                      pro_embed, skill_embed, ans_embed,
                                      ls_state, pro_state0, skill_state0,
                                      akt_diff, akt_change,
                                      TEpf, TEsf, CAF,
                                      Ppf, Psf, Paf, Pas, Pps, Pss, Po1,
                                      bas, bps, bss, bo1, Wo2, bo2,
                                      ps, ssb, out);
}